// Round 10
// baseline (761.050 us; speedup 1.0000x reference)
//
#include <hip/hip_runtime.h>
#include <math.h>

#define N_NODES 100000
#define N_EDGES 3200000
#define NCLASS  64
#define TOPK    16
#define NHID    128
#define DEG     6

#define NBUCK   391          // ceil(100000/256) buckets of 256 rows
#define NSEG    8            // independent fill streams per bucket
#define SEGCAP  1408         // per (bucket,segment); mean 1023

#define EB ((N_EDGES + 255) / 256)               // 12500 scatter blocks
#define GNODES 32                                 // nodes per gating block
#define GB ((N_NODES + GNODES - 1) / GNODES)      // 3125 gating blocks

// ---------- bf16 helpers ----------
__device__ __forceinline__ float bf2f(unsigned short u) {
    return __uint_as_float(((unsigned)u) << 16);
}
__device__ __forceinline__ unsigned short f2bf(float f) {
    unsigned u = __float_as_uint(f);
    u = (u + 0x7FFFu + ((u >> 16) & 1u)) >> 16;   // round-to-nearest-even
    return (unsigned short)u;
}

// ---------- fused scatter + gating, INTERLEAVED (idx%5==0 -> gating) ----------
// r6-proven version (single launch; r9's 3-chunk diagnostic cost ~57us and
// is reverted now that spmm counters are captured).
__global__ __launch_bounds__(256) void scatter_gating_kernel(
        const int* __restrict__ erow, const int* __restrict__ ecol,
        const float* __restrict__ eval, int* __restrict__ fill,
        int2* __restrict__ staging,
        const float* __restrict__ x,  const float* __restrict__ W1,
        const float* __restrict__ b1, const float* __restrict__ W2,
        const float* __restrict__ b2, float* __restrict__ weight,
        float* __restrict__ out_acc, unsigned short* __restrict__ xbf) {
    __shared__ float sW1t[TOPK * NHID];
    __shared__ float sb1[NHID];
    __shared__ float sW2[DEG * NHID];
    __shared__ float sb2[DEG];

    unsigned bi = blockIdx.x;
    if (bi % 5 != 0) {
        // ----- scatter path: scatter_id = bi - bi/5 - 1 -----
        int sid = (int)(bi - bi / 5u - 1u);
        int i = sid * 256 + threadIdx.x;
        // XCD-local segment (blockIdx%8 ~ XCD id, round-robin dispatch)
        int s = (int)(bi & 7u);
        if (i < N_EDGES) {
            int   r = __builtin_nontemporal_load(&erow[i]);
            int   c = __builtin_nontemporal_load(&ecol[i]);
            float w = __builtin_nontemporal_load(&eval[i]);
            int b = r >> 8;
            int pos = atomicAdd(&fill[(s * NBUCK + b) * 16], 1);
            if (pos < SEGCAP) {
                int2 e;
                e.x = (c << 8) | (r & 255);   // col:17b << 8 | row_local:8b
                e.y = __float_as_int(w);
                staging[((size_t)b * NSEG + s) * SEGCAP + pos] = e;
            }
        }
        return;
    }

    // ----- gating path: gating_id = bi/5 -----
    int gb = (int)(bi / 5u);
    int tid = threadIdx.x;
    for (int idx = tid; idx < NHID * TOPK; idx += 256) {
        int k = idx / NHID, j = idx - k * NHID;
        sW1t[idx] = W1[j * TOPK + k];
    }
    for (int i = tid; i < NHID; i += 256) sb1[i] = b1[i];
    for (int i = tid; i < DEG * NHID; i += 256) sW2[i] = W2[i];
    if (tid < DEG) sb2[tid] = b2[tid];
    __syncthreads();

    int wave = tid >> 6;
    int lane = tid & 63;

    // 3125*32 = 100000 exactly: no bounds checks needed.
    for (int it = 0; it < GNODES / 8; it++) {
        int nA = gb * GNODES + it * 8 + wave;
        int nB = nA + 4;

        float xA = x[nA * NCLASS + lane];
        float xB = x[nB * NCLASS + lane];
        xbf[nA * NCLASS + lane] = f2bf(xA);
        xbf[nB * NCLASS + lane] = f2bf(xB);

        // two interleaved ascending bitonic sorts (softmax monotonic ->
        // top-16 of p == softmax of top-16 of x)
        float vA = xA, vB = xB;
        #pragma unroll
        for (int k = 2; k <= 64; k <<= 1) {
            #pragma unroll
            for (int j = k >> 1; j > 0; j >>= 1) {
                float oA = __shfl_xor(vA, j);
                float oB = __shfl_xor(vB, j);
                bool keep_small = (((lane & j) == 0) == ((lane & k) == 0));
                vA = keep_small ? fminf(vA, oA) : fmaxf(vA, oA);
                vB = keep_small ? fminf(vB, oB) : fmaxf(vB, oB);
            }
        }
        float mA = __shfl(vA, 63), mB = __shfl(vB, 63);
        float eA = __expf(vA - mA), eB = __expf(vB - mB);
        float sA = eA, sB = eB;
        #pragma unroll
        for (int off = 1; off < 64; off <<= 1) {
            sA += __shfl_xor(sA, off);
            sB += __shfl_xor(sB, off);
        }
        float invA = 1.0f / sA, invB = 1.0f / sB;

        float h0A = sb1[lane], h1A = sb1[lane + 64];
        float h0B = h0A,       h1B = h1A;
        #pragma unroll
        for (int k = 0; k < TOPK; k++) {
            float svA = __shfl(vA, 63 - k);
            float svB = __shfl(vB, 63 - k);
            float w1a = sW1t[k * NHID + lane];
            float w1b = sW1t[k * NHID + lane + 64];
            float tkA = __expf(svA - mA) * invA;
            float tkB = __expf(svB - mB) * invB;
            h0A += tkA * w1a; h1A += tkA * w1b;
            h0B += tkB * w1a; h1B += tkB * w1b;
        }
        h0A = (h0A > 0.f) ? h0A : 0.1f * h0A;
        h1A = (h1A > 0.f) ? h1A : 0.1f * h1A;
        h0B = (h0B > 0.f) ? h0B : 0.1f * h0B;
        h1B = (h1B > 0.f) ? h1B : 0.1f * h1B;

        float wA[DEG], wB[DEG];
        float wmA = -1e30f, wmB = -1e30f;
        #pragma unroll
        for (int d = 0; d < DEG; d++) {
            float w2a = sW2[d * NHID + lane];
            float w2b = sW2[d * NHID + lane + 64];
            float pA = h0A * w2a + h1A * w2b;
            float pB = h0B * w2a + h1B * w2b;
            #pragma unroll
            for (int off = 1; off < 64; off <<= 1) {
                pA += __shfl_xor(pA, off);
                pB += __shfl_xor(pB, off);
            }
            wA[d] = pA + sb2[d];
            wB[d] = pB + sb2[d];
            wmA = fmaxf(wmA, wA[d]);
            wmB = fmaxf(wmB, wB[d]);
        }
        float wsA = 0.f, wsB = 0.f;
        #pragma unroll
        for (int d = 0; d < DEG; d++) {
            wA[d] = __expf(wA[d] - wmA); wsA += wA[d];
            wB[d] = __expf(wB[d] - wmB); wsB += wB[d];
        }
        float iwA = 1.0f / wsA, iwB = 1.0f / wsB;

        if (lane < DEG) {
            weight[nA * DEG + lane] = wA[lane] * iwA;
            weight[nB * DEG + lane] = wB[lane] * iwB;
        }
        out_acc[nA * NCLASS + lane] = wA[0] * iwA * xA;
        out_acc[nB * NCLASS + lane] = wB[0] * iwB * xB;
    }
}

// ---------- phase 2: per-bucket compaction + row_ptr (inline prefix base) ----------
__global__ __launch_bounds__(256) void phase2_build(
        const int2* __restrict__ staging, const int* __restrict__ fill,
        int* __restrict__ row_ptr, int2* __restrict__ edges_s) {
    __shared__ int lred[256];
    __shared__ int lhist[256];
    __shared__ int lscan[256];
    __shared__ int lfill[256];
    __shared__ int sseg[NSEG];
    int b = blockIdx.x, tid = threadIdx.x;

    int part = 0;
    for (int j = tid; j < b; j += 256) {
        int t = 0;
        #pragma unroll
        for (int s = 0; s < NSEG; s++) t += min(fill[(s * NBUCK + j) * 16], SEGCAP);
        part += t;
    }
    lred[tid] = part;
    if (tid < NSEG) sseg[tid] = min(fill[(tid * NBUCK + b) * 16], SEGCAP);
    __syncthreads();
    for (int off = 128; off > 0; off >>= 1) {
        if (tid < off) lred[tid] += lred[tid + off];
        __syncthreads();
    }
    int base_b = lred[0];

    lhist[tid] = 0;
    __syncthreads();
    for (int s = 0; s < NSEG; s++) {
        int c = sseg[s];
        const int2* seg = staging + ((size_t)b * NSEG + s) * SEGCAP;
        for (int j = tid; j < c; j += 256) atomicAdd(&lhist[seg[j].x & 255], 1);
    }
    __syncthreads();
    int v = lhist[tid];
    lscan[tid] = v;
    __syncthreads();
    for (int off = 1; off < 256; off <<= 1) {
        int t = (tid >= off) ? lscan[tid - off] : 0;
        __syncthreads();
        lscan[tid] += t;
        __syncthreads();
    }
    int excl = base_b + (lscan[tid] - v);
    int grow = b * 256 + tid;
    if (grow < N_NODES) row_ptr[grow] = excl;
    if (b == NBUCK - 1 && tid == 255) row_ptr[N_NODES] = excl + v;
    lfill[tid] = excl;
    __syncthreads();
    for (int s = 0; s < NSEG; s++) {
        int c = sseg[s];
        const int2* seg = staging + ((size_t)b * NSEG + s) * SEGCAP;
        for (int j = tid; j < c; j += 256) {
            int2 e = seg[j];
            int rl = e.x & 255;
            int pos = atomicAdd(&lfill[rl], 1);
            edges_s[pos] = make_int2((int)(((unsigned)e.x) >> 8), e.y);
        }
    }
}

// ---------- SPMM gather groups ----------
// r9 counters: VALUBusy 52% == 4 VALU/edge (2 readfirstlane + lshl + fmac).
// r10: drop BOTH readfirstlanes — the uniform edge quad is already
// wave-uniform in VGPRs: col used directly via zext 32-bit offset
// ((col<<6)+lane -> v_lshl_add_u32 + saddr global_load), weight = hi dword
// used directly as fmac operand. VALU/edge 4 -> 3, SALU addr removed, dep
// chain 1 stage shorter. Gathers nontemporal (L1 hit ~0 on 12.8MB random;
// bypass may deepen fill concurrency).
__device__ __forceinline__ void gather8(const unsigned short* __restrict__ src,
                                        const long long* __restrict__ edq,
                                        int e, unsigned lane, float& acc) {
    long long q[8];
    #pragma unroll
    for (int k = 0; k < 8; k++) q[k] = __builtin_nontemporal_load(&edq[e + k]);
    float vk[8], fk[8];
    #pragma unroll
    for (int k = 0; k < 8; k++) {
        unsigned col = (unsigned)(unsigned int)q[k];
        vk[k] = __int_as_float((int)(q[k] >> 32));
        fk[k] = bf2f(__builtin_nontemporal_load(&src[(col << 6) + lane]));
    }
    #pragma unroll
    for (int k = 0; k < 8; k++) acc += vk[k] * fk[k];
}

__device__ __forceinline__ void gather4(const unsigned short* __restrict__ src,
                                        const long long* __restrict__ edq,
                                        int e, unsigned lane, float& acc) {
    long long q[4];
    #pragma unroll
    for (int k = 0; k < 4; k++) q[k] = __builtin_nontemporal_load(&edq[e + k]);
    float vk[4], fk[4];
    #pragma unroll
    for (int k = 0; k < 4; k++) {
        unsigned col = (unsigned)(unsigned int)q[k];
        vk[k] = __int_as_float((int)(q[k] >> 32));
        fk[k] = bf2f(__builtin_nontemporal_load(&src[(col << 6) + lane]));
    }
    #pragma unroll
    for (int k = 0; k < 4; k++) acc += vk[k] * fk[k];
}

__device__ __forceinline__ void gather1(const unsigned short* __restrict__ src,
                                        const long long* __restrict__ edq,
                                        int e, unsigned lane, float& acc) {
    long long q0 = __builtin_nontemporal_load(&edq[e]);
    unsigned col = (unsigned)(unsigned int)q0;
    float v0 = __int_as_float((int)(q0 >> 32));
    acc += v0 * bf2f(__builtin_nontemporal_load(&src[(col << 6) + lane]));
}

// ---------- SPMM hop: wave per 4 ROWS (r6 structure, lean gather feed) ----
// mode 0: write dst only.
// mode 1: write dst AND out_acc += w[hop-1]*src[node] + w[hop]*acc.
// mode 3: last hop — v = out_acc + w[hop-2]*prev2 + w[hop-1]*src + w[hop]*acc
//         -> log_softmax -> final_out.
__global__ __launch_bounds__(256) void spmm_kernel(
        const unsigned short* __restrict__ src, unsigned short* __restrict__ dst,
        const unsigned short* __restrict__ prev2,
        const int* __restrict__ row_ptr, const int2* __restrict__ edges_s,
        const float* __restrict__ weight,
        float* __restrict__ out_acc, float* __restrict__ final_out,
        int hop, int mode) {
    int wave = threadIdx.x >> 6;
    unsigned lane = threadIdx.x & 63;
    int wid = blockIdx.x * 4 + wave;          // 0..24999
    int r0 = wid * 4;
    if (r0 >= N_NODES) return;                 // exact fit: 25000*4 = 100000

    int p0 = __builtin_amdgcn_readfirstlane(row_ptr[r0]);
    int p1 = __builtin_amdgcn_readfirstlane(row_ptr[r0 + 1]);
    int p2 = __builtin_amdgcn_readfirstlane(row_ptr[r0 + 2]);
    int p3 = __builtin_amdgcn_readfirstlane(row_ptr[r0 + 3]);
    int p4 = __builtin_amdgcn_readfirstlane(row_ptr[r0 + 4]);

    const long long* edq = (const long long*)edges_s;
    float acc[4] = {0.f, 0.f, 0.f, 0.f};
    int e0 = p0, e1 = p1, e2 = p2, e3 = p3;

    // phase A: lockstep straight-line block — 32 gathers in flight
    while (e0 + 8 <= p1 && e1 + 8 <= p2 && e2 + 8 <= p3 && e3 + 8 <= p4) {
        gather8(src, edq, e0, lane, acc[0]);
        gather8(src, edq, e1, lane, acc[1]);
        gather8(src, edq, e2, lane, acc[2]);
        gather8(src, edq, e3, lane, acc[3]);
        e0 += 8; e1 += 8; e2 += 8; e3 += 8;
    }
    // phase B: per-chain gather8 until each chain individually drops below 8
    for (;;) {
        bool b0 = (e0 + 8 <= p1), b1 = (e1 + 8 <= p2);
        bool b2 = (e2 + 8 <= p3), b3 = (e3 + 8 <= p4);
        if (!(b0 || b1 || b2 || b3)) break;
        if (b0) { gather8(src, edq, e0, lane, acc[0]); e0 += 8; }
        if (b1) { gather8(src, edq, e1, lane, acc[1]); e1 += 8; }
        if (b2) { gather8(src, edq, e2, lane, acc[2]); e2 += 8; }
        if (b3) { gather8(src, edq, e3, lane, acc[3]); e3 += 8; }
    }
    // phase C: interleaved gather4 drain — up to 16 in flight
    for (;;) {
        bool b0 = (e0 + 4 <= p1), b1 = (e1 + 4 <= p2);
        bool b2 = (e2 + 4 <= p3), b3 = (e3 + 4 <= p4);
        if (!(b0 || b1 || b2 || b3)) break;
        if (b0) { gather4(src, edq, e0, lane, acc[0]); e0 += 4; }
        if (b1) { gather4(src, edq, e1, lane, acc[1]); e1 += 4; }
        if (b2) { gather4(src, edq, e2, lane, acc[2]); e2 += 4; }
        if (b3) { gather4(src, edq, e3, lane, acc[3]); e3 += 4; }
    }
    // phase D: interleaved scalar tail (<=3 edges/chain)
    for (;;) {
        bool b0 = (e0 < p1), b1 = (e1 < p2), b2 = (e2 < p3), b3 = (e3 < p4);
        if (!(b0 || b1 || b2 || b3)) break;
        if (b0) { gather1(src, edq, e0, lane, acc[0]); e0++; }
        if (b1) { gather1(src, edq, e1, lane, acc[1]); e1++; }
        if (b2) { gather1(src, edq, e2, lane, acc[2]); e2++; }
        if (b3) { gather1(src, edq, e3, lane, acc[3]); e3++; }
    }

    #pragma unroll
    for (int k = 0; k < 4; k++) {
        int r = r0 + k;
        float a = acc[k];
        float w = weight[r * DEG + hop];
        if (mode == 0) {
            dst[r * NCLASS + lane] = f2bf(a);
        } else if (mode == 1) {
            dst[r * NCLASS + lane] = f2bf(a);
            float p  = bf2f(src[r * NCLASS + lane]);   // prev hop out, coalesced
            float wp = weight[r * DEG + hop - 1];
            out_acc[r * NCLASS + lane] += wp * p + w * a;
        } else {
            float q1 = bf2f(src[r * NCLASS + lane]);    // hop-1 output
            float q2 = bf2f(prev2[r * NCLASS + lane]);  // hop-2 output
            float v = out_acc[r * NCLASS + lane]
                    + weight[r * DEG + hop - 2] * q2
                    + weight[r * DEG + hop - 1] * q1 + w * a;
            float m = 0.f;
            {
                float t = v;
                #pragma unroll
                for (int off = 1; off < 64; off <<= 1) t = fmaxf(t, __shfl_xor(t, off));
                m = t;
            }
            float ee = __expf(v - m);
            float ss = ee;
            #pragma unroll
            for (int off = 1; off < 64; off <<= 1) ss += __shfl_xor(ss, off);
            final_out[r * NCLASS + lane] = v - m - __logf(ss);
        }
    }
}

extern "C" void kernel_launch(void* const* d_in, const int* in_sizes, int n_in,
                              void* d_out, int out_size, void* d_ws, size_t ws_size,
                              hipStream_t stream) {
    const float* x    = (const float*)d_in[0];
    const int*   erow = (const int*)  d_in[1];
    const int*   ecol = (const int*)  d_in[2];
    const float* eval = (const float*)d_in[3];
    const float* W1   = (const float*)d_in[4];
    const float* b1   = (const float*)d_in[5];
    const float* W2   = (const float*)d_in[6];
    const float* b2   = (const float*)d_in[7];
    float* out = (float*)d_out;   // also the hop-accumulation buffer

    char* ws = (char*)d_ws;
    size_t off = 0;
    auto alloc = [&](size_t bytes) -> void* {
        void* p = ws + off;
        off = (off + bytes + 255) & ~(size_t)255;
        return p;
    };
    // staging (35.2 MB) is dead after phase2; cur0/cur1 (25.6 MB) reuse it.
    // xbf is SEPARATE: gating writes it concurrently with the scatter.
    char* regionS = (char*)alloc((size_t)NBUCK * NSEG * SEGCAP * 8);   // 35.2 MB
    int2* staging = (int2*)regionS;
    unsigned short* cur0 = (unsigned short*)regionS;
    unsigned short* cur1 = (unsigned short*)(regionS + (size_t)N_NODES * NCLASS * 2);
    unsigned short* xbf  = (unsigned short*)alloc((size_t)N_NODES * NCLASS * 2);

    int2*  edges_s = (int2*)alloc((size_t)N_EDGES * 8);
    int*   row_ptr = (int*) alloc((size_t)(N_NODES + 1) * 4);
    int*   fill    = (int*) alloc((size_t)NSEG * NBUCK * 16 * 4);   // 64B-padded
    float* weight  = (float*)alloc((size_t)N_NODES * DEG * 4);

    const int WB = (N_NODES / 4 + 3) / 4;            // 6250 (4 waves x 4 rows)

    hipMemsetAsync(fill, 0, (size_t)NSEG * NBUCK * 16 * 4, stream);
    // fused: scatter (12500) + gating (3125) interleaved every 5th block
    scatter_gating_kernel<<<EB + GB, 256, 0, stream>>>(
        erow, ecol, eval, fill, staging, x, W1, b1, W2, b2, weight, out, xbf);
    phase2_build<<<NBUCK, 256, 0, stream>>>(staging, fill, row_ptr, edges_s);

    // 5 hops; h2 folds (w1,w2), h5 folds (w3,w4,w5) + log_softmax
    spmm_kernel<<<WB, 256, 0, stream>>>(xbf,  cur0, cur0, row_ptr, edges_s, weight, out, out, 1, 0);
    spmm_kernel<<<WB, 256, 0, stream>>>(cur0, cur1, cur0, row_ptr, edges_s, weight, out, out, 2, 1);
    spmm_kernel<<<WB, 256, 0, stream>>>(cur1, cur0, cur0, row_ptr, edges_s, weight, out, out, 3, 0);
    spmm_kernel<<<WB, 256, 0, stream>>>(cur0, cur1, cur0, row_ptr, edges_s, weight, out, out, 4, 0);
    spmm_kernel<<<WB, 256, 0, stream>>>(cur1, cur0, cur0, row_ptr, edges_s, weight, out, out, 5, 3);
}

// Round 11
// 663.586 us; speedup vs baseline: 1.1469x; 1.1469x over previous
//
#include <hip/hip_runtime.h>
#include <math.h>

#define N_NODES 100000
#define N_EDGES 3200000
#define NCLASS  64
#define TOPK    16
#define NHID    128
#define DEG     6

#define NBUCK   391          // ceil(100000/256) buckets of 256 rows
#define NSEG    8            // independent fill streams per bucket
#define SEGCAP  1408         // per (bucket,segment); mean 1023

#define GNODES 32                                 // nodes per gating block
#define GB ((N_NODES + GNODES - 1) / GNODES)      // 3125 gating blocks
#define SGB 6256             // 782 groups of 8 (even grp=gating, odd=scatter)

// ---------- bf16 helpers ----------
__device__ __forceinline__ float bf2f(unsigned short u) {
    return __uint_as_float(((unsigned)u) << 16);
}
__device__ __forceinline__ unsigned short f2bf(float f) {
    unsigned u = __float_as_uint(f);
    u = (u + 0x7FFFu + ((u >> 16) & 1u)) >> 16;   // round-to-nearest-even
    return (unsigned short)u;
}

// ---------- fused scatter + gating ----------
// r10 post-mortem: 12500 one-edge-per-thread scatter blocks caused block
// churn (occ 35% with NO static limiter). r11: 4 edges/thread via int4/
// float4 loads -> 3125 scatter blocks. Interleave in GROUPS OF 8 (even
// group = gating, odd = scatter) so both populations cover all 8 XCDs;
// s = bi&7 stays XCD-local for fill atomics + staging write fronts.
__global__ __launch_bounds__(256) void scatter_gating_kernel(
        const int* __restrict__ erow, const int* __restrict__ ecol,
        const float* __restrict__ eval, int* __restrict__ fill,
        int2* __restrict__ staging,
        const float* __restrict__ x,  const float* __restrict__ W1,
        const float* __restrict__ b1, const float* __restrict__ W2,
        const float* __restrict__ b2, float* __restrict__ weight,
        float* __restrict__ out_acc, unsigned short* __restrict__ xbf) {
    __shared__ float sW1t[TOPK * NHID];
    __shared__ float sb1[NHID];
    __shared__ float sW2[DEG * NHID];
    __shared__ float sb2[DEG];

    unsigned bi = blockIdx.x;
    unsigned grp = bi >> 3;
    unsigned slot = bi & 7u;

    if (grp & 1u) {
        // ----- scatter path: 4 edges per thread, vectorized loads -----
        int sid = (int)((grp >> 1) * 8 + slot);
        if (sid < GB) {
            int gid = sid * 256 + (int)threadIdx.x;     // quad index
            int4   r4 = ((const int4*)erow)[gid];
            int4   c4 = ((const int4*)ecol)[gid];
            float4 w4 = ((const float4*)eval)[gid];
            int s = (int)slot;                           // XCD-local segment
            int rr[4] = {r4.x, r4.y, r4.z, r4.w};
            int cc[4] = {c4.x, c4.y, c4.z, c4.w};
            float ww[4] = {w4.x, w4.y, w4.z, w4.w};
            #pragma unroll
            for (int k = 0; k < 4; k++) {
                int b = rr[k] >> 8;
                int pos = atomicAdd(&fill[(s * NBUCK + b) * 16], 1);
                if (pos < SEGCAP) {
                    int2 e;
                    e.x = (cc[k] << 8) | (rr[k] & 255);  // col<<8 | row_local
                    e.y = __float_as_int(ww[k]);
                    staging[((size_t)b * NSEG + s) * SEGCAP + pos] = e;
                }
            }
        }
        return;
    }

    // ----- gating path -----
    int gb = (int)((grp >> 1) * 8 + slot);
    if (gb >= GB) return;
    int tid = threadIdx.x;
    for (int idx = tid; idx < NHID * TOPK; idx += 256) {
        int k = idx / NHID, j = idx - k * NHID;
        sW1t[idx] = W1[j * TOPK + k];
    }
    for (int i = tid; i < NHID; i += 256) sb1[i] = b1[i];
    for (int i = tid; i < DEG * NHID; i += 256) sW2[i] = W2[i];
    if (tid < DEG) sb2[tid] = b2[tid];
    __syncthreads();

    int wave = tid >> 6;
    int lane = tid & 63;

    // 3125*32 = 100000 exactly: no bounds checks needed.
    for (int it = 0; it < GNODES / 8; it++) {
        int nA = gb * GNODES + it * 8 + wave;
        int nB = nA + 4;

        float xA = x[nA * NCLASS + lane];
        float xB = x[nB * NCLASS + lane];
        xbf[nA * NCLASS + lane] = f2bf(xA);
        xbf[nB * NCLASS + lane] = f2bf(xB);

        // two interleaved ascending bitonic sorts (softmax monotonic ->
        // top-16 of p == softmax of top-16 of x)
        float vA = xA, vB = xB;
        #pragma unroll
        for (int k = 2; k <= 64; k <<= 1) {
            #pragma unroll
            for (int j = k >> 1; j > 0; j >>= 1) {
                float oA = __shfl_xor(vA, j);
                float oB = __shfl_xor(vB, j);
                bool keep_small = (((lane & j) == 0) == ((lane & k) == 0));
                vA = keep_small ? fminf(vA, oA) : fmaxf(vA, oA);
                vB = keep_small ? fminf(vB, oB) : fmaxf(vB, oB);
            }
        }
        float mA = __shfl(vA, 63), mB = __shfl(vB, 63);
        float eA = __expf(vA - mA), eB = __expf(vB - mB);
        float sA = eA, sB = eB;
        #pragma unroll
        for (int off = 1; off < 64; off <<= 1) {
            sA += __shfl_xor(sA, off);
            sB += __shfl_xor(sB, off);
        }
        float invA = 1.0f / sA, invB = 1.0f / sB;

        float h0A = sb1[lane], h1A = sb1[lane + 64];
        float h0B = h0A,       h1B = h1A;
        #pragma unroll
        for (int k = 0; k < TOPK; k++) {
            float svA = __shfl(vA, 63 - k);
            float svB = __shfl(vB, 63 - k);
            float w1a = sW1t[k * NHID + lane];
            float w1b = sW1t[k * NHID + lane + 64];
            float tkA = __expf(svA - mA) * invA;
            float tkB = __expf(svB - mB) * invB;
            h0A += tkA * w1a; h1A += tkA * w1b;
            h0B += tkB * w1a; h1B += tkB * w1b;
        }
        h0A = (h0A > 0.f) ? h0A : 0.1f * h0A;
        h1A = (h1A > 0.f) ? h1A : 0.1f * h1A;
        h0B = (h0B > 0.f) ? h0B : 0.1f * h0B;
        h1B = (h1B > 0.f) ? h1B : 0.1f * h1B;

        float wA[DEG], wB[DEG];
        float wmA = -1e30f, wmB = -1e30f;
        #pragma unroll
        for (int d = 0; d < DEG; d++) {
            float w2a = sW2[d * NHID + lane];
            float w2b = sW2[d * NHID + lane + 64];
            float pA = h0A * w2a + h1A * w2b;
            float pB = h0B * w2a + h1B * w2b;
            #pragma unroll
            for (int off = 1; off < 64; off <<= 1) {
                pA += __shfl_xor(pA, off);
                pB += __shfl_xor(pB, off);
            }
            wA[d] = pA + sb2[d];
            wB[d] = pB + sb2[d];
            wmA = fmaxf(wmA, wA[d]);
            wmB = fmaxf(wmB, wB[d]);
        }
        float wsA = 0.f, wsB = 0.f;
        #pragma unroll
        for (int d = 0; d < DEG; d++) {
            wA[d] = __expf(wA[d] - wmA); wsA += wA[d];
            wB[d] = __expf(wB[d] - wmB); wsB += wB[d];
        }
        float iwA = 1.0f / wsA, iwB = 1.0f / wsB;

        if (lane < DEG) {
            weight[nA * DEG + lane] = wA[lane] * iwA;
            weight[nB * DEG + lane] = wB[lane] * iwB;
        }
        out_acc[nA * NCLASS + lane] = wA[0] * iwA * xA;
        out_acc[nB * NCLASS + lane] = wB[0] * iwB * xB;
    }
}

// ---------- phase 2: per-bucket compaction + row_ptr (inline prefix base) ----------
__global__ __launch_bounds__(256) void phase2_build(
        const int2* __restrict__ staging, const int* __restrict__ fill,
        int* __restrict__ row_ptr, int2* __restrict__ edges_s) {
    __shared__ int lred[256];
    __shared__ int lhist[256];
    __shared__ int lscan[256];
    __shared__ int lfill[256];
    __shared__ int sseg[NSEG];
    int b = blockIdx.x, tid = threadIdx.x;

    int part = 0;
    for (int j = tid; j < b; j += 256) {
        int t = 0;
        #pragma unroll
        for (int s = 0; s < NSEG; s++) t += min(fill[(s * NBUCK + j) * 16], SEGCAP);
        part += t;
    }
    lred[tid] = part;
    if (tid < NSEG) sseg[tid] = min(fill[(tid * NBUCK + b) * 16], SEGCAP);
    __syncthreads();
    for (int off = 128; off > 0; off >>= 1) {
        if (tid < off) lred[tid] += lred[tid + off];
        __syncthreads();
    }
    int base_b = lred[0];

    lhist[tid] = 0;
    __syncthreads();
    for (int s = 0; s < NSEG; s++) {
        int c = sseg[s];
        const int2* seg = staging + ((size_t)b * NSEG + s) * SEGCAP;
        for (int j = tid; j < c; j += 256) atomicAdd(&lhist[seg[j].x & 255], 1);
    }
    __syncthreads();
    int v = lhist[tid];
    lscan[tid] = v;
    __syncthreads();
    for (int off = 1; off < 256; off <<= 1) {
        int t = (tid >= off) ? lscan[tid - off] : 0;
        __syncthreads();
        lscan[tid] += t;
        __syncthreads();
    }
    int excl = base_b + (lscan[tid] - v);
    int grow = b * 256 + tid;
    if (grow < N_NODES) row_ptr[grow] = excl;
    if (b == NBUCK - 1 && tid == 255) row_ptr[N_NODES] = excl + v;
    lfill[tid] = excl;
    __syncthreads();
    for (int s = 0; s < NSEG; s++) {
        int c = sseg[s];
        const int2* seg = staging + ((size_t)b * NSEG + s) * SEGCAP;
        for (int j = tid; j < c; j += 256) {
            int2 e = seg[j];
            int rl = e.x & 255;
            int pos = atomicAdd(&lfill[rl], 1);
            edges_s[pos] = make_int2((int)(((unsigned)e.x) >> 8), e.y);
        }
    }
}

// ---------- SPMM gather groups (r6-proven: scalar SGPR edge stream) ----------
// r8/r10 post-mortems: BOTH alternates (readlane feed, VGPR-addressed nt
// gather) regressed. The scalar edge stream (readfirstlane -> SGPR base,
// L1 allocation on) is load-bearing. Do not touch.
__device__ __forceinline__ void gather8(const unsigned short* __restrict__ src,
                                        const long long* __restrict__ edq,
                                        int e, int lane, float& acc) {
    long long q[8];
    #pragma unroll
    for (int k = 0; k < 8; k++) q[k] = __builtin_nontemporal_load(&edq[e + k]);
    float vk[8], fk[8];
    #pragma unroll
    for (int k = 0; k < 8; k++) {
        int col = __builtin_amdgcn_readfirstlane((int)(unsigned)q[k]);
        vk[k] = __int_as_float(__builtin_amdgcn_readfirstlane((int)(q[k] >> 32)));
        fk[k] = bf2f(src[col * NCLASS + lane]);
    }
    #pragma unroll
    for (int k = 0; k < 8; k++) acc += vk[k] * fk[k];
}

__device__ __forceinline__ void gather4(const unsigned short* __restrict__ src,
                                        const long long* __restrict__ edq,
                                        int e, int lane, float& acc) {
    long long q[4];
    #pragma unroll
    for (int k = 0; k < 4; k++) q[k] = __builtin_nontemporal_load(&edq[e + k]);
    float vk[4], fk[4];
    #pragma unroll
    for (int k = 0; k < 4; k++) {
        int col = __builtin_amdgcn_readfirstlane((int)(unsigned)q[k]);
        vk[k] = __int_as_float(__builtin_amdgcn_readfirstlane((int)(q[k] >> 32)));
        fk[k] = bf2f(src[col * NCLASS + lane]);
    }
    #pragma unroll
    for (int k = 0; k < 4; k++) acc += vk[k] * fk[k];
}

__device__ __forceinline__ void gather1(const unsigned short* __restrict__ src,
                                        const long long* __restrict__ edq,
                                        int e, int lane, float& acc) {
    long long q0 = __builtin_nontemporal_load(&edq[e]);
    int   c0 = __builtin_amdgcn_readfirstlane((int)(unsigned)q0);
    float v0 = __int_as_float(__builtin_amdgcn_readfirstlane((int)(q0 >> 32)));
    acc += v0 * bf2f(src[c0 * NCLASS + lane]);
}

// ---------- SPMM hop: wave per 4 ROWS (r6-proven structure) ----------
// mode 0: write dst only.
// mode 1: write dst AND out_acc += w[hop-1]*src[node] + w[hop]*acc.
// mode 3: last hop — v = out_acc + w[hop-2]*prev2 + w[hop-1]*src + w[hop]*acc
//         -> log_softmax -> final_out.
__global__ __launch_bounds__(256) void spmm_kernel(
        const unsigned short* __restrict__ src, unsigned short* __restrict__ dst,
        const unsigned short* __restrict__ prev2,
        const int* __restrict__ row_ptr, const int2* __restrict__ edges_s,
        const float* __restrict__ weight,
        float* __restrict__ out_acc, float* __restrict__ final_out,
        int hop, int mode) {
    int wave = threadIdx.x >> 6;
    int lane = threadIdx.x & 63;
    int wid = blockIdx.x * 4 + wave;          // 0..24999
    int r0 = wid * 4;
    if (r0 >= N_NODES) return;                 // exact fit: 25000*4 = 100000

    int p0 = __builtin_amdgcn_readfirstlane(row_ptr[r0]);
    int p1 = __builtin_amdgcn_readfirstlane(row_ptr[r0 + 1]);
    int p2 = __builtin_amdgcn_readfirstlane(row_ptr[r0 + 2]);
    int p3 = __builtin_amdgcn_readfirstlane(row_ptr[r0 + 3]);
    int p4 = __builtin_amdgcn_readfirstlane(row_ptr[r0 + 4]);

    const long long* edq = (const long long*)edges_s;
    float acc[4] = {0.f, 0.f, 0.f, 0.f};
    int e0 = p0, e1 = p1, e2 = p2, e3 = p3;

    // phase A: lockstep straight-line block — 32 gathers in flight
    while (e0 + 8 <= p1 && e1 + 8 <= p2 && e2 + 8 <= p3 && e3 + 8 <= p4) {
        gather8(src, edq, e0, lane, acc[0]);
        gather8(src, edq, e1, lane, acc[1]);
        gather8(src, edq, e2, lane, acc[2]);
        gather8(src, edq, e3, lane, acc[3]);
        e0 += 8; e1 += 8; e2 += 8; e3 += 8;
    }
    // phase B: per-chain gather8 until each chain individually drops below 8
    for (;;) {
        bool b0 = (e0 + 8 <= p1), b1 = (e1 + 8 <= p2);
        bool b2 = (e2 + 8 <= p3), b3 = (e3 + 8 <= p4);
        if (!(b0 || b1 || b2 || b3)) break;
        if (b0) { gather8(src, edq, e0, lane, acc[0]); e0 += 8; }
        if (b1) { gather8(src, edq, e1, lane, acc[1]); e1 += 8; }
        if (b2) { gather8(src, edq, e2, lane, acc[2]); e2 += 8; }
        if (b3) { gather8(src, edq, e3, lane, acc[3]); e3 += 8; }
    }
    // phase C: interleaved gather4 drain — up to 16 in flight
    for (;;) {
        bool b0 = (e0 + 4 <= p1), b1 = (e1 + 4 <= p2);
        bool b2 = (e2 + 4 <= p3), b3 = (e3 + 4 <= p4);
        if (!(b0 || b1 || b2 || b3)) break;
        if (b0) { gather4(src, edq, e0, lane, acc[0]); e0 += 4; }
        if (b1) { gather4(src, edq, e1, lane, acc[1]); e1 += 4; }
        if (b2) { gather4(src, edq, e2, lane, acc[2]); e2 += 4; }
        if (b3) { gather4(src, edq, e3, lane, acc[3]); e3 += 4; }
    }
    // phase D: interleaved scalar tail (<=3 edges/chain)
    for (;;) {
        bool b0 = (e0 < p1), b1 = (e1 < p2), b2 = (e2 < p3), b3 = (e3 < p4);
        if (!(b0 || b1 || b2 || b3)) break;
        if (b0) { gather1(src, edq, e0, lane, acc[0]); e0++; }
        if (b1) { gather1(src, edq, e1, lane, acc[1]); e1++; }
        if (b2) { gather1(src, edq, e2, lane, acc[2]); e2++; }
        if (b3) { gather1(src, edq, e3, lane, acc[3]); e3++; }
    }

    #pragma unroll
    for (int k = 0; k < 4; k++) {
        int r = r0 + k;
        float a = acc[k];
        float w = weight[r * DEG + hop];
        if (mode == 0) {
            dst[r * NCLASS + lane] = f2bf(a);
        } else if (mode == 1) {
            dst[r * NCLASS + lane] = f2bf(a);
            float p  = bf2f(src[r * NCLASS + lane]);   // prev hop out, coalesced
            float wp = weight[r * DEG + hop - 1];
            out_acc[r * NCLASS + lane] += wp * p + w * a;
        } else {
            float q1 = bf2f(src[r * NCLASS + lane]);    // hop-1 output
            float q2 = bf2f(prev2[r * NCLASS + lane]);  // hop-2 output
            float v = out_acc[r * NCLASS + lane]
                    + weight[r * DEG + hop - 2] * q2
                    + weight[r * DEG + hop - 1] * q1 + w * a;
            float m = 0.f;
            {
                float t = v;
                #pragma unroll
                for (int off = 1; off < 64; off <<= 1) t = fmaxf(t, __shfl_xor(t, off));
                m = t;
            }
            float ee = __expf(v - m);
            float ss = ee;
            #pragma unroll
            for (int off = 1; off < 64; off <<= 1) ss += __shfl_xor(ss, off);
            final_out[r * NCLASS + lane] = v - m - __logf(ss);
        }
    }
}

extern "C" void kernel_launch(void* const* d_in, const int* in_sizes, int n_in,
                              void* d_out, int out_size, void* d_ws, size_t ws_size,
                              hipStream_t stream) {
    const float* x    = (const float*)d_in[0];
    const int*   erow = (const int*)  d_in[1];
    const int*   ecol = (const int*)  d_in[2];
    const float* eval = (const float*)d_in[3];
    const float* W1   = (const float*)d_in[4];
    const float* b1   = (const float*)d_in[5];
    const float* W2   = (const float*)d_in[6];
    const float* b2   = (const float*)d_in[7];
    float* out = (float*)d_out;   // also the hop-accumulation buffer

    char* ws = (char*)d_ws;
    size_t off = 0;
    auto alloc = [&](size_t bytes) -> void* {
        void* p = ws + off;
        off = (off + bytes + 255) & ~(size_t)255;
        return p;
    };
    // staging (35.2 MB) is dead after phase2; cur0/cur1 (25.6 MB) reuse it.
    // xbf is SEPARATE: gating writes it concurrently with the scatter.
    char* regionS = (char*)alloc((size_t)NBUCK * NSEG * SEGCAP * 8);   // 35.2 MB
    int2* staging = (int2*)regionS;
    unsigned short* cur0 = (unsigned short*)regionS;
    unsigned short* cur1 = (unsigned short*)(regionS + (size_t)N_NODES * NCLASS * 2);
    unsigned short* xbf  = (unsigned short*)alloc((size_t)N_NODES * NCLASS * 2);

    int2*  edges_s = (int2*)alloc((size_t)N_EDGES * 8);
    int*   row_ptr = (int*) alloc((size_t)(N_NODES + 1) * 4);
    int*   fill    = (int*) alloc((size_t)NSEG * NBUCK * 16 * 4);   // 64B-padded
    float* weight  = (float*)alloc((size_t)N_NODES * DEG * 4);

    const int WB = (N_NODES / 4 + 3) / 4;            // 6250 (4 waves x 4 rows)

    hipMemsetAsync(fill, 0, (size_t)NSEG * NBUCK * 16 * 4, stream);
    // fused: gating/scatter in alternating groups of 8 blocks (all XCDs)
    scatter_gating_kernel<<<SGB, 256, 0, stream>>>(
        erow, ecol, eval, fill, staging, x, W1, b1, W2, b2, weight, out, xbf);
    phase2_build<<<NBUCK, 256, 0, stream>>>(staging, fill, row_ptr, edges_s);

    // 5 hops; h2 folds (w1,w2), h5 folds (w3,w4,w5) + log_softmax
    spmm_kernel<<<WB, 256, 0, stream>>>(xbf,  cur0, cur0, row_ptr, edges_s, weight, out, out, 1, 0);
    spmm_kernel<<<WB, 256, 0, stream>>>(cur0, cur1, cur0, row_ptr, edges_s, weight, out, out, 2, 1);
    spmm_kernel<<<WB, 256, 0, stream>>>(cur1, cur0, cur0, row_ptr, edges_s, weight, out, out, 3, 0);
    spmm_kernel<<<WB, 256, 0, stream>>>(cur0, cur1, cur0, row_ptr, edges_s, weight, out, out, 4, 0);
    spmm_kernel<<<WB, 256, 0, stream>>>(cur1, cur0, cur0, row_ptr, edges_s, weight, out, out, 5, 3);
}

// Round 12
// 646.445 us; speedup vs baseline: 1.1773x; 1.0265x over previous
//
#include <hip/hip_runtime.h>
#include <math.h>

#define N_NODES 100000
#define N_EDGES 3200000
#define NCLASS  64
#define TOPK    16
#define NHID    128
#define DEG     6

#define NBUCK   391          // ceil(100000/256) buckets of 256 rows
#define NSEG    8            // independent fill streams per bucket
#define SEGCAP  1408         // per (bucket,segment); mean 1023

#define EB ((N_EDGES + 255) / 256)               // 12500 scatter blocks
#define GNODES 32                                 // nodes per gating block
#define GB ((N_NODES + GNODES - 1) / GNODES)      // 3125 gating blocks

// ---------- bf16 helpers ----------
__device__ __forceinline__ float bf2f(unsigned short u) {
    return __uint_as_float(((unsigned)u) << 16);
}
__device__ __forceinline__ unsigned short f2bf(float f) {
    unsigned u = __float_as_uint(f);
    u = (u + 0x7FFFu + ((u >> 16) & 1u)) >> 16;   // round-to-nearest-even
    return (unsigned short)u;
}

// ---------- fused scatter + gating, INTERLEAVED (idx%5==0 -> gating) ----------
// r6-proven version. r11 post-mortem: 4-edge/thread scatter REGRESSED
// (175->207us, occ 35->27%) — the 12500 tiny scatter blocks' TLP is what
// hides the atomic latency. Do not repack.
__global__ __launch_bounds__(256) void scatter_gating_kernel(
        const int* __restrict__ erow, const int* __restrict__ ecol,
        const float* __restrict__ eval, int* __restrict__ fill,
        int2* __restrict__ staging,
        const float* __restrict__ x,  const float* __restrict__ W1,
        const float* __restrict__ b1, const float* __restrict__ W2,
        const float* __restrict__ b2, float* __restrict__ weight,
        float* __restrict__ out_acc, unsigned short* __restrict__ xbf) {
    __shared__ float sW1t[TOPK * NHID];
    __shared__ float sb1[NHID];
    __shared__ float sW2[DEG * NHID];
    __shared__ float sb2[DEG];

    unsigned bi = blockIdx.x;
    if (bi % 5 != 0) {
        // ----- scatter path: scatter_id = bi - bi/5 - 1 -----
        int sid = (int)(bi - bi / 5u - 1u);
        int i = sid * 256 + threadIdx.x;
        // XCD-local segment (blockIdx%8 ~ XCD id, round-robin dispatch)
        int s = (int)(bi & 7u);
        if (i < N_EDGES) {
            int   r = __builtin_nontemporal_load(&erow[i]);
            int   c = __builtin_nontemporal_load(&ecol[i]);
            float w = __builtin_nontemporal_load(&eval[i]);
            int b = r >> 8;
            int pos = atomicAdd(&fill[(s * NBUCK + b) * 16], 1);
            if (pos < SEGCAP) {
                int2 e;
                e.x = (c << 8) | (r & 255);   // col:17b << 8 | row_local:8b
                e.y = __float_as_int(w);
                staging[((size_t)b * NSEG + s) * SEGCAP + pos] = e;
            }
        }
        return;
    }

    // ----- gating path: gating_id = bi/5 -----
    int gb = (int)(bi / 5u);
    int tid = threadIdx.x;
    for (int idx = tid; idx < NHID * TOPK; idx += 256) {
        int k = idx / NHID, j = idx - k * NHID;
        sW1t[idx] = W1[j * TOPK + k];
    }
    for (int i = tid; i < NHID; i += 256) sb1[i] = b1[i];
    for (int i = tid; i < DEG * NHID; i += 256) sW2[i] = W2[i];
    if (tid < DEG) sb2[tid] = b2[tid];
    __syncthreads();

    int wave = tid >> 6;
    int lane = tid & 63;

    // 3125*32 = 100000 exactly: no bounds checks needed.
    for (int it = 0; it < GNODES / 8; it++) {
        int nA = gb * GNODES + it * 8 + wave;
        int nB = nA + 4;

        float xA = x[nA * NCLASS + lane];
        float xB = x[nB * NCLASS + lane];
        xbf[nA * NCLASS + lane] = f2bf(xA);
        xbf[nB * NCLASS + lane] = f2bf(xB);

        // two interleaved ascending bitonic sorts (softmax monotonic ->
        // top-16 of p == softmax of top-16 of x)
        float vA = xA, vB = xB;
        #pragma unroll
        for (int k = 2; k <= 64; k <<= 1) {
            #pragma unroll
            for (int j = k >> 1; j > 0; j >>= 1) {
                float oA = __shfl_xor(vA, j);
                float oB = __shfl_xor(vB, j);
                bool keep_small = (((lane & j) == 0) == ((lane & k) == 0));
                vA = keep_small ? fminf(vA, oA) : fmaxf(vA, oA);
                vB = keep_small ? fminf(vB, oB) : fmaxf(vB, oB);
            }
        }
        float mA = __shfl(vA, 63), mB = __shfl(vB, 63);
        float eA = __expf(vA - mA), eB = __expf(vB - mB);
        float sA = eA, sB = eB;
        #pragma unroll
        for (int off = 1; off < 64; off <<= 1) {
            sA += __shfl_xor(sA, off);
            sB += __shfl_xor(sB, off);
        }
        float invA = 1.0f / sA, invB = 1.0f / sB;

        float h0A = sb1[lane], h1A = sb1[lane + 64];
        float h0B = h0A,       h1B = h1A;
        #pragma unroll
        for (int k = 0; k < TOPK; k++) {
            float svA = __shfl(vA, 63 - k);
            float svB = __shfl(vB, 63 - k);
            float w1a = sW1t[k * NHID + lane];
            float w1b = sW1t[k * NHID + lane + 64];
            float tkA = __expf(svA - mA) * invA;
            float tkB = __expf(svB - mB) * invB;
            h0A += tkA * w1a; h1A += tkA * w1b;
            h0B += tkB * w1a; h1B += tkB * w1b;
        }
        h0A = (h0A > 0.f) ? h0A : 0.1f * h0A;
        h1A = (h1A > 0.f) ? h1A : 0.1f * h1A;
        h0B = (h0B > 0.f) ? h0B : 0.1f * h0B;
        h1B = (h1B > 0.f) ? h1B : 0.1f * h1B;

        float wA[DEG], wB[DEG];
        float wmA = -1e30f, wmB = -1e30f;
        #pragma unroll
        for (int d = 0; d < DEG; d++) {
            float w2a = sW2[d * NHID + lane];
            float w2b = sW2[d * NHID + lane + 64];
            float pA = h0A * w2a + h1A * w2b;
            float pB = h0B * w2a + h1B * w2b;
            #pragma unroll
            for (int off = 1; off < 64; off <<= 1) {
                pA += __shfl_xor(pA, off);
                pB += __shfl_xor(pB, off);
            }
            wA[d] = pA + sb2[d];
            wB[d] = pB + sb2[d];
            wmA = fmaxf(wmA, wA[d]);
            wmB = fmaxf(wmB, wB[d]);
        }
        float wsA = 0.f, wsB = 0.f;
        #pragma unroll
        for (int d = 0; d < DEG; d++) {
            wA[d] = __expf(wA[d] - wmA); wsA += wA[d];
            wB[d] = __expf(wB[d] - wmB); wsB += wB[d];
        }
        float iwA = 1.0f / wsA, iwB = 1.0f / wsB;

        if (lane < DEG) {
            weight[nA * DEG + lane] = wA[lane] * iwA;
            weight[nB * DEG + lane] = wB[lane] * iwB;
        }
        out_acc[nA * NCLASS + lane] = wA[0] * iwA * xA;
        out_acc[nB * NCLASS + lane] = wB[0] * iwB * xB;
    }
}

// ---------- phase 2: per-bucket compaction + row_ptr (inline prefix base) ----------
__global__ __launch_bounds__(256) void phase2_build(
        const int2* __restrict__ staging, const int* __restrict__ fill,
        int* __restrict__ row_ptr, int2* __restrict__ edges_s) {
    __shared__ int lred[256];
    __shared__ int lhist[256];
    __shared__ int lscan[256];
    __shared__ int lfill[256];
    __shared__ int sseg[NSEG];
    int b = blockIdx.x, tid = threadIdx.x;

    int part = 0;
    for (int j = tid; j < b; j += 256) {
        int t = 0;
        #pragma unroll
        for (int s = 0; s < NSEG; s++) t += min(fill[(s * NBUCK + j) * 16], SEGCAP);
        part += t;
    }
    lred[tid] = part;
    if (tid < NSEG) sseg[tid] = min(fill[(tid * NBUCK + b) * 16], SEGCAP);
    __syncthreads();
    for (int off = 128; off > 0; off >>= 1) {
        if (tid < off) lred[tid] += lred[tid + off];
        __syncthreads();
    }
    int base_b = lred[0];

    lhist[tid] = 0;
    __syncthreads();
    for (int s = 0; s < NSEG; s++) {
        int c = sseg[s];
        const int2* seg = staging + ((size_t)b * NSEG + s) * SEGCAP;
        for (int j = tid; j < c; j += 256) atomicAdd(&lhist[seg[j].x & 255], 1);
    }
    __syncthreads();
    int v = lhist[tid];
    lscan[tid] = v;
    __syncthreads();
    for (int off = 1; off < 256; off <<= 1) {
        int t = (tid >= off) ? lscan[tid - off] : 0;
        __syncthreads();
        lscan[tid] += t;
        __syncthreads();
    }
    int excl = base_b + (lscan[tid] - v);
    int grow = b * 256 + tid;
    if (grow < N_NODES) row_ptr[grow] = excl;
    if (b == NBUCK - 1 && tid == 255) row_ptr[N_NODES] = excl + v;
    lfill[tid] = excl;
    __syncthreads();
    for (int s = 0; s < NSEG; s++) {
        int c = sseg[s];
        const int2* seg = staging + ((size_t)b * NSEG + s) * SEGCAP;
        for (int j = tid; j < c; j += 256) {
            int2 e = seg[j];
            int rl = e.x & 255;
            int pos = atomicAdd(&lfill[rl], 1);
            edges_s[pos] = make_int2((int)(((unsigned)e.x) >> 8), e.y);
        }
    }
}

// ---------- SPMM gather groups (r6-proven: scalar SGPR edge stream) ----------
// r8/r10 post-mortems: BOTH alternates (readlane feed, VGPR-addressed nt
// gather) regressed. The scalar edge stream (readfirstlane -> SGPR base,
// L1 allocation on) is load-bearing. Do not touch.
__device__ __forceinline__ void gather8(const unsigned short* __restrict__ src,
                                        const long long* __restrict__ edq,
                                        int e, int lane, float& acc) {
    long long q[8];
    #pragma unroll
    for (int k = 0; k < 8; k++) q[k] = __builtin_nontemporal_load(&edq[e + k]);
    float vk[8], fk[8];
    #pragma unroll
    for (int k = 0; k < 8; k++) {
        int col = __builtin_amdgcn_readfirstlane((int)(unsigned)q[k]);
        vk[k] = __int_as_float(__builtin_amdgcn_readfirstlane((int)(q[k] >> 32)));
        fk[k] = bf2f(src[col * NCLASS + lane]);
    }
    #pragma unroll
    for (int k = 0; k < 8; k++) acc += vk[k] * fk[k];
}

__device__ __forceinline__ void gather4(const unsigned short* __restrict__ src,
                                        const long long* __restrict__ edq,
                                        int e, int lane, float& acc) {
    long long q[4];
    #pragma unroll
    for (int k = 0; k < 4; k++) q[k] = __builtin_nontemporal_load(&edq[e + k]);
    float vk[4], fk[4];
    #pragma unroll
    for (int k = 0; k < 4; k++) {
        int col = __builtin_amdgcn_readfirstlane((int)(unsigned)q[k]);
        vk[k] = __int_as_float(__builtin_amdgcn_readfirstlane((int)(q[k] >> 32)));
        fk[k] = bf2f(src[col * NCLASS + lane]);
    }
    #pragma unroll
    for (int k = 0; k < 4; k++) acc += vk[k] * fk[k];
}

__device__ __forceinline__ void gather1(const unsigned short* __restrict__ src,
                                        const long long* __restrict__ edq,
                                        int e, int lane, float& acc) {
    long long q0 = __builtin_nontemporal_load(&edq[e]);
    int   c0 = __builtin_amdgcn_readfirstlane((int)(unsigned)q0);
    float v0 = __int_as_float(__builtin_amdgcn_readfirstlane((int)(q0 >> 32)));
    acc += v0 * bf2f(src[c0 * NCLASS + lane]);
}

// ---------- SPMM hop: wave per 4 ROWS, 128-THREAD BLOCKS ----------
// r12: spmm has NO __syncthreads and NO LDS — its 4 waves/block were fully
// independent, yet a 256-thread block only retires when its slowest wave
// finishes (row-length variance) -> observed occupancy 63% with nothing
// static capping it. 2-wave blocks halve the retirement granule and raise
// the resident-wave ceiling (16 WG/CU x 2 = 32 waves/CU).
// mode 0: write dst only.
// mode 1: write dst AND out_acc += w[hop-1]*src[node] + w[hop]*acc.
// mode 3: last hop — v = out_acc + w[hop-2]*prev2 + w[hop-1]*src + w[hop]*acc
//         -> log_softmax -> final_out.
__global__ __launch_bounds__(128) void spmm_kernel(
        const unsigned short* __restrict__ src, unsigned short* __restrict__ dst,
        const unsigned short* __restrict__ prev2,
        const int* __restrict__ row_ptr, const int2* __restrict__ edges_s,
        const float* __restrict__ weight,
        float* __restrict__ out_acc, float* __restrict__ final_out,
        int hop, int mode) {
    int wave = threadIdx.x >> 6;
    int lane = threadIdx.x & 63;
    int wid = blockIdx.x * 2 + wave;          // 0..24999
    int r0 = wid * 4;
    if (r0 >= N_NODES) return;                 // exact fit: 12500*2*4 = 100000

    int p0 = __builtin_amdgcn_readfirstlane(row_ptr[r0]);
    int p1 = __builtin_amdgcn_readfirstlane(row_ptr[r0 + 1]);
    int p2 = __builtin_amdgcn_readfirstlane(row_ptr[r0 + 2]);
    int p3 = __builtin_amdgcn_readfirstlane(row_ptr[r0 + 3]);
    int p4 = __builtin_amdgcn_readfirstlane(row_ptr[r0 + 4]);

    const long long* edq = (const long long*)edges_s;
    float acc[4] = {0.f, 0.f, 0.f, 0.f};
    int e0 = p0, e1 = p1, e2 = p2, e3 = p3;

    // phase A: lockstep straight-line block — 32 gathers in flight
    while (e0 + 8 <= p1 && e1 + 8 <= p2 && e2 + 8 <= p3 && e3 + 8 <= p4) {
        gather8(src, edq, e0, lane, acc[0]);
        gather8(src, edq, e1, lane, acc[1]);
        gather8(src, edq, e2, lane, acc[2]);
        gather8(src, edq, e3, lane, acc[3]);
        e0 += 8; e1 += 8; e2 += 8; e3 += 8;
    }
    // phase B: per-chain gather8 until each chain individually drops below 8
    for (;;) {
        bool b0 = (e0 + 8 <= p1), b1 = (e1 + 8 <= p2);
        bool b2 = (e2 + 8 <= p3), b3 = (e3 + 8 <= p4);
        if (!(b0 || b1 || b2 || b3)) break;
        if (b0) { gather8(src, edq, e0, lane, acc[0]); e0 += 8; }
        if (b1) { gather8(src, edq, e1, lane, acc[1]); e1 += 8; }
        if (b2) { gather8(src, edq, e2, lane, acc[2]); e2 += 8; }
        if (b3) { gather8(src, edq, e3, lane, acc[3]); e3 += 8; }
    }
    // phase C: interleaved gather4 drain — up to 16 in flight
    for (;;) {
        bool b0 = (e0 + 4 <= p1), b1 = (e1 + 4 <= p2);
        bool b2 = (e2 + 4 <= p3), b3 = (e3 + 4 <= p4);
        if (!(b0 || b1 || b2 || b3)) break;
        if (b0) { gather4(src, edq, e0, lane, acc[0]); e0 += 4; }
        if (b1) { gather4(src, edq, e1, lane, acc[1]); e1 += 4; }
        if (b2) { gather4(src, edq, e2, lane, acc[2]); e2 += 4; }
        if (b3) { gather4(src, edq, e3, lane, acc[3]); e3 += 4; }
    }
    // phase D: interleaved scalar tail (<=3 edges/chain)
    for (;;) {
        bool b0 = (e0 < p1), b1 = (e1 < p2), b2 = (e2 < p3), b3 = (e3 < p4);
        if (!(b0 || b1 || b2 || b3)) break;
        if (b0) { gather1(src, edq, e0, lane, acc[0]); e0++; }
        if (b1) { gather1(src, edq, e1, lane, acc[1]); e1++; }
        if (b2) { gather1(src, edq, e2, lane, acc[2]); e2++; }
        if (b3) { gather1(src, edq, e3, lane, acc[3]); e3++; }
    }

    #pragma unroll
    for (int k = 0; k < 4; k++) {
        int r = r0 + k;
        float a = acc[k];
        float w = weight[r * DEG + hop];
        if (mode == 0) {
            dst[r * NCLASS + lane] = f2bf(a);
        } else if (mode == 1) {
            dst[r * NCLASS + lane] = f2bf(a);
            float p  = bf2f(src[r * NCLASS + lane]);   // prev hop out, coalesced
            float wp = weight[r * DEG + hop - 1];
            out_acc[r * NCLASS + lane] += wp * p + w * a;
        } else {
            float q1 = bf2f(src[r * NCLASS + lane]);    // hop-1 output
            float q2 = bf2f(prev2[r * NCLASS + lane]);  // hop-2 output
            float v = out_acc[r * NCLASS + lane]
                    + weight[r * DEG + hop - 2] * q2
                    + weight[r * DEG + hop - 1] * q1 + w * a;
            float m = 0.f;
            {
                float t = v;
                #pragma unroll
                for (int off = 1; off < 64; off <<= 1) t = fmaxf(t, __shfl_xor(t, off));
                m = t;
            }
            float ee = __expf(v - m);
            float ss = ee;
            #pragma unroll
            for (int off = 1; off < 64; off <<= 1) ss += __shfl_xor(ss, off);
            final_out[r * NCLASS + lane] = v - m - __logf(ss);
        }
    }
}

extern "C" void kernel_launch(void* const* d_in, const int* in_sizes, int n_in,
                              void* d_out, int out_size, void* d_ws, size_t ws_size,
                              hipStream_t stream) {
    const float* x    = (const float*)d_in[0];
    const int*   erow = (const int*)  d_in[1];
    const int*   ecol = (const int*)  d_in[2];
    const float* eval = (const float*)d_in[3];
    const float* W1   = (const float*)d_in[4];
    const float* b1   = (const float*)d_in[5];
    const float* W2   = (const float*)d_in[6];
    const float* b2   = (const float*)d_in[7];
    float* out = (float*)d_out;   // also the hop-accumulation buffer

    char* ws = (char*)d_ws;
    size_t off = 0;
    auto alloc = [&](size_t bytes) -> void* {
        void* p = ws + off;
        off = (off + bytes + 255) & ~(size_t)255;
        return p;
    };
    // staging (35.2 MB) is dead after phase2; cur0/cur1 (25.6 MB) reuse it.
    // xbf is SEPARATE: gating writes it concurrently with the scatter.
    char* regionS = (char*)alloc((size_t)NBUCK * NSEG * SEGCAP * 8);   // 35.2 MB
    int2* staging = (int2*)regionS;
    unsigned short* cur0 = (unsigned short*)regionS;
    unsigned short* cur1 = (unsigned short*)(regionS + (size_t)N_NODES * NCLASS * 2);
    unsigned short* xbf  = (unsigned short*)alloc((size_t)N_NODES * NCLASS * 2);

    int2*  edges_s = (int2*)alloc((size_t)N_EDGES * 8);
    int*   row_ptr = (int*) alloc((size_t)(N_NODES + 1) * 4);
    int*   fill    = (int*) alloc((size_t)NSEG * NBUCK * 16 * 4);   // 64B-padded
    float* weight  = (float*)alloc((size_t)N_NODES * DEG * 4);

    const int WB2 = N_NODES / 8;                     // 12500 (2 waves x 4 rows)

    hipMemsetAsync(fill, 0, (size_t)NSEG * NBUCK * 16 * 4, stream);
    // fused: scatter (12500) + gating (3125) interleaved every 5th block
    scatter_gating_kernel<<<EB + GB, 256, 0, stream>>>(
        erow, ecol, eval, fill, staging, x, W1, b1, W2, b2, weight, out, xbf);
    phase2_build<<<NBUCK, 256, 0, stream>>>(staging, fill, row_ptr, edges_s);

    // 5 hops; h2 folds (w1,w2), h5 folds (w3,w4,w5) + log_softmax
    spmm_kernel<<<WB2, 128, 0, stream>>>(xbf,  cur0, cur0, row_ptr, edges_s, weight, out, out, 1, 0);
    spmm_kernel<<<WB2, 128, 0, stream>>>(cur0, cur1, cur0, row_ptr, edges_s, weight, out, out, 2, 1);
    spmm_kernel<<<WB2, 128, 0, stream>>>(cur1, cur0, cur0, row_ptr, edges_s, weight, out, out, 3, 0);
    spmm_kernel<<<WB2, 128, 0, stream>>>(cur0, cur1, cur0, row_ptr, edges_s, weight, out, out, 4, 0);
    spmm_kernel<<<WB2, 128, 0, stream>>>(cur1, cur0, cur0, row_ptr, edges_s, weight, out, out, 5, 3);
}